// Round 5
// baseline (267.753 us; speedup 1.0000x reference)
//
#include <hip/hip_runtime.h>
#include <stdint.h>

// XOR chain = inclusive prefix-XOR along axis 0 of [S=4096, B=8192] int32.
// Round 19: two-pass reduce-then-scan, replacing decoupled lookback with a
// dispatch boundary. Rationale: R14/R17/R18 single-variable experiments
// exonerated load engine, occupancy, ticket, and store flavor -- all land at
// ~82us, 2x over the ~45us roofline. The shared suspect is the single-dispatch
// lookback structure: all blocks finish loading at the same instant, so reads
// and writes phase-serialize AND the whole grid polls the LLC coherence point
// at the worst moment. Two passes delete that machinery entirely:
//   pass 1 (reduce): DMA-staged read + per-chunk agg nibble -> 512KB table.
//     No atomics. Rocprof row = pure read-phase measurement.
//   pass 2 (scan): reload input (LLC-resident after pass 1), XOR <=63 cached
//     table words as seed (guaranteed present -- no polls), scan, NT store
//     (NT preserves input LLC residency during the pass).
// Per-dispatch predictions: reduce 12-20us FETCH~67-128MB WRITE~0.5MB;
// scan 22-30us FETCH<20MB WRITE~132MB. Whichever row blows its budget
// localizes the remaining tax.

#define S 4096
#define B4 2048               // v4u column-groups per row
#define TPB 512
#define NCT (B4 / TPB)        // 4 coltiles
#define OUTER 64              // rows per chunk
#define NOUT (S / OUTER)      // 64 chunk-rows
#define NBLK (NOUT * NCT)     // 256 blocks, 1/CU, all resident
#define NWORDS (NOUT * B4)    // 128K dwords = 512 KB agg table
#define STG 4                 // rows per stage
#define NSTG (OUTER / STG)    // 16 stages

typedef unsigned int v4u __attribute__((ext_vector_type(4)));
typedef unsigned long long u64;
typedef const __attribute__((address_space(1))) v4u* gp1_t;
typedef __attribute__((address_space(3))) v4u* lp3_t;

__device__ __forceinline__ u64 repl(unsigned nib) {   // nibble -> 16 copies
    u64 m = nib;
    m |= m << 4; m |= m << 8; m |= m << 16; m |= m << 32;
    return m;
}

// R17-proven DMA-staged load of 64 rows (16 stages x 4 rows, double-buffered,
// hand-counted vmcnt), packing one nibble per row into q[4] (4 bits x 64 rows).
__device__ __forceinline__ void load_pack(const v4u* __restrict__ p,
                                          v4u (*sh)[STG][TPB],
                                          int tid, int wbase, u64 q[4]) {
    auto STAGE = [&](int srow, int buf) {
#pragma unroll
        for (int j = 0; j < STG; ++j)
            __builtin_amdgcn_global_load_lds(
                (gp1_t)(const void*)(p + (size_t)(srow + j) * B4),
                (lp3_t)(void*)&sh[buf][j][wbase], 16, 0, 0);
    };
    q[0] = q[1] = q[2] = q[3] = 0ull;
    STAGE(0, 0);
    STAGE(STG, 1);
#pragma unroll
    for (int s = 0; s < NSTG; ++s) {
        if (s < NSTG - 1) asm volatile("s_waitcnt vmcnt(4)" ::: "memory");
        else              asm volatile("s_waitcnt vmcnt(0)" ::: "memory");
        const int buf = s & 1;
#pragma unroll
        for (int j = 0; j < STG; ++j) {
            v4u v = sh[buf][j][tid];
            unsigned n = (v.x & 1u) | ((v.y & 1u) << 1) |
                         ((v.z & 1u) << 2) | ((v.w & 1u) << 3);
            const int r = s * STG + j;
            q[r >> 4] ^= (u64)n << (4 * (r & 15));
        }
        asm volatile("s_waitcnt lgkmcnt(0)" ::: "memory");
        if (s + 2 < NSTG) STAGE((s + 2) * STG, buf);
    }
}

__global__ __launch_bounds__(TPB) void xor_reduce(
        const v4u* __restrict__ in, unsigned* __restrict__ agg) {
    __shared__ v4u sh[2][STG][TPB];   // 64 KB
    const int tid   = (int)threadIdx.x;
    const int bid   = (int)blockIdx.x;
    const int ct    = bid & (NCT - 1);
    const int o     = bid >> 2;
    const int colg  = ct * TPB + tid;
    const int wbase = tid & ~63;

    u64 q[4];
    load_pack(in + (size_t)o * OUTER * B4 + colg, sh, tid, wbase, q);

    u64 tt = q[0] ^ q[1] ^ q[2] ^ q[3];
    tt ^= tt >> 32; tt ^= tt >> 16; tt ^= tt >> 8; tt ^= tt >> 4;
    agg[(size_t)o * B4 + colg] = (unsigned)tt & 0xFu;   // plain store
}

__global__ __launch_bounds__(TPB) void xor_scan(
        const v4u* __restrict__ in, v4u* __restrict__ out,
        const unsigned* __restrict__ agg) {
    __shared__ v4u sh[2][STG][TPB];   // 64 KB
    const int tid   = (int)threadIdx.x;
    const int bid   = (int)blockIdx.x;
    const int ct    = bid & (NCT - 1);
    const int o     = bid >> 2;
    const int colg  = ct * TPB + tid;
    const int wbase = tid & ~63;

    u64 q[4];
    load_pack(in + (size_t)o * OUTER * B4 + colg, sh, tid, wbase, q);

    // Exclusive seed: XOR of predecessor chunk aggregates (table written by
    // pass 1; dispatch ordering guarantees visibility -- no polling).
    unsigned ex = 0u;
    for (int k = 0; k < o; ++k)
        ex ^= agg[(size_t)k * B4 + colg];
    ex &= 0xFu;

    // ---- Scan (4 shift-XOR steps per u64), seed, unpack, NT store ----
    unsigned carry = ex;
    v4u* qo = out + (size_t)o * OUTER * B4 + colg;
#pragma unroll
    for (int kk = 0; kk < 4; ++kk) {
        u64 x = q[kk];
        x ^= x << 4; x ^= x << 8; x ^= x << 16; x ^= x << 32;  // prefix-XOR
        const u64 f = x ^ repl(carry);
        carry ^= (unsigned)(x >> 60) & 0xFu;
#pragma unroll
        for (int j = 0; j < 16; ++j) {
            const unsigned n = (unsigned)(f >> (4 * j)) & 0xFu;
            v4u ov = (v4u){n & 1u, (n >> 1) & 1u, (n >> 2) & 1u, (n >> 3) & 1u};
            __builtin_nontemporal_store(ov, &qo[(size_t)(kk * 16 + j) * B4]);
        }
    }
}

extern "C" void kernel_launch(void* const* d_in, const int* in_sizes, int n_in,
                              void* d_out, int out_size, void* d_ws, size_t ws_size,
                              hipStream_t stream) {
    const v4u* in = (const v4u*)d_in[0];
    v4u* out = (v4u*)d_out;
    unsigned* agg = (unsigned*)d_ws;  // 512 KB table; fully written by pass 1

    xor_reduce<<<NBLK, TPB, 0, stream>>>(in, agg);
    xor_scan<<<NBLK, TPB, 0, stream>>>(in, out, agg);
}

// Round 6
// 237.632 us; speedup vs baseline: 1.1268x; 1.1268x over previous
//
#include <hip/hip_runtime.h>
#include <stdint.h>

// XOR chain = inclusive prefix-XOR along axis 0 of [S=4096, B=8192] int32.
// Round 20: SINGLE-VARIABLE test — global_load_lds aux 0 -> 1 (sc0).
// Evidence chain: R19's pure-read reduce pass ran ~55us (2.4 TB/s) with no
// stores/atomics/lookback => reads are the bottleneck everywhere. R14 (32KB/CU
// in flight) == R17 (48-64KB/CU) == 2.5 TB/s: for that to be latency-bound
// needs ~12000cy latency (implausible) => reads are throughput-capped at
// ~4KB/CU real concurrency = per-CU L1/TCP MSHR limit. Writes skip MSHRs
// (fill = 6.7 TB/s). Fix under test: sc0 (SE scope) on the LDS-DMA loads
// bypasses the TCP lookup, keeps L2+LLC, moves concurrency to per-channel
// TCC MSHRs. Everything else byte-identical to R17 (83.7us base).
// Predict: if TCP-cap right, kernel -> 58-68us (bench 210-222); if null,
// fabric read cap ~2.5 TB/s stands and R21 overlaps write under read.

#define S 4096
#define B4 2048               // v4u column-groups per row
#define TPB 512
#define NCT (B4 / TPB)        // 4 coltiles
#define OUTER 64              // rows per chunk
#define NOUT (S / OUTER)      // 64 chunk-rows
#define NBLK (NOUT * NCT)     // 256 blocks, 1/CU, all resident
#define NWORDS (NOUT * B4)    // 128K dwords = 512 KB per table
#define POISON 0xAAAAAAAAu
#define STG 4                 // rows per stage
#define NSTG (OUTER / STG)    // 16 stages

typedef unsigned int v4u __attribute__((ext_vector_type(4)));
typedef unsigned long long u64;
typedef const __attribute__((address_space(1))) v4u* gp1_t;
typedef __attribute__((address_space(3))) v4u* lp3_t;

__device__ __forceinline__ bool valid(unsigned w) {
    return (w & 0x300u) == 0x100u;   // 0xAAAAAAAA poison and 0 both fail
}
__device__ __forceinline__ u64 repl(unsigned nib) {   // nibble -> 16 copies
    u64 m = nib;
    m |= m << 4; m |= m << 8; m |= m << 16; m |= m << 32;
    return m;
}

__global__ __launch_bounds__(TPB) void xor_sc0(
        const v4u* __restrict__ in, v4u* __restrict__ out,
        unsigned* __restrict__ ctl) {
    unsigned* agg = ctl + 64;
    unsigned* inc = agg + NWORDS;

    __shared__ v4u sh[2][STG][TPB];   // 64 KB, per-wave-private slabs

    const int tid   = (int)threadIdx.x;
    const int bid   = (int)blockIdx.x;
    const int ct    = bid & (NCT - 1);
    const int o     = bid >> 2;              // NCT = 4
    const int colg  = ct * TPB + tid;
    const int wbase = tid & ~63;             // wave-uniform lane base

    const v4u* p = in + (size_t)o * OUTER * B4 + colg;

    // ---- DMA-staged load: aux=1 (sc0, SE scope) => bypass CU-L1/TCP ----
    auto STAGE = [&](int srow, int buf) {
#pragma unroll
        for (int j = 0; j < STG; ++j)
            __builtin_amdgcn_global_load_lds(
                (gp1_t)(const void*)(p + (size_t)(srow + j) * B4),
                (lp3_t)(void*)&sh[buf][j][wbase], 16, 0, 1 /*sc0*/);
    };

    u64 q[4] = {0ull, 0ull, 0ull, 0ull};
    STAGE(0, 0);
    STAGE(STG, 1);
#pragma unroll
    for (int s = 0; s < NSTG; ++s) {
        if (s < NSTG - 1) asm volatile("s_waitcnt vmcnt(4)" ::: "memory");
        else              asm volatile("s_waitcnt vmcnt(0)" ::: "memory");
        const int buf = s & 1;
#pragma unroll
        for (int j = 0; j < STG; ++j) {
            v4u v = sh[buf][j][tid];
            unsigned n = (v.x & 1u) | ((v.y & 1u) << 1) |
                         ((v.z & 1u) << 2) | ((v.w & 1u) << 3);
            const int r = s * STG + j;
            q[r >> 4] ^= (u64)n << (4 * (r & 15));
        }
        // ds_reads fully retired before the DMA can overwrite this buffer
        asm volatile("s_waitcnt lgkmcnt(0)" ::: "memory");
        if (s + 2 < NSTG) STAGE((s + 2) * STG, buf);
    }

    // ---- Publish aggregate nibble (XOR of all 64 row-nibbles) ----
    u64 tt = q[0] ^ q[1] ^ q[2] ^ q[3];
    tt ^= tt >> 32; tt ^= tt >> 16; tt ^= tt >> 8; tt ^= tt >> 4;
    const unsigned myagg = (unsigned)tt & 0xFu;
    __hip_atomic_store(&agg[(size_t)o * B4 + colg], 0x100u | myagg,
                       __ATOMIC_RELAXED, __HIP_MEMORY_SCOPE_AGENT);

    // ---- Lookback: inc fast path + 16-wide batched agg polls ----
    unsigned ex = 0u;
    int k = o - 1;
    while (k >= 0) {
        unsigned iw = __hip_atomic_load(&inc[(size_t)k * B4 + colg],
                                        __ATOMIC_RELAXED,
                                        __HIP_MEMORY_SCOPE_AGENT);
        if (valid(iw)) { ex ^= (iw & 0xFu); break; }
        int n = (k + 1 < 16) ? (k + 1) : 16;
        unsigned a[16];
        for (int j = 0; j < n; ++j)
            a[j] = __hip_atomic_load(&agg[(size_t)(k - j) * B4 + colg],
                                     __ATOMIC_RELAXED,
                                     __HIP_MEMORY_SCOPE_AGENT);
        int consumed = 0;
        for (int j = 0; j < n; ++j) {
            if (valid(a[j])) { ex ^= (a[j] & 0xFu); ++consumed; }
            else break;
        }
        k -= consumed;
        if (consumed == 0) __builtin_amdgcn_s_sleep(1);
    }
    __hip_atomic_store(&inc[(size_t)o * B4 + colg], 0x100u | (ex ^ myagg),
                       __ATOMIC_RELAXED, __HIP_MEMORY_SCOPE_AGENT);

    // ---- Scan (4 shift-XOR steps per u64), seed, unpack, NT store ----
    unsigned carry = ex;
    v4u* qo = out + (size_t)o * OUTER * B4 + colg;
#pragma unroll
    for (int kk = 0; kk < 4; ++kk) {
        u64 x = q[kk];
        x ^= x << 4; x ^= x << 8; x ^= x << 16; x ^= x << 32;  // prefix-XOR
        const u64 f = x ^ repl(carry);
        carry ^= (unsigned)(x >> 60) & 0xFu;
#pragma unroll
        for (int j = 0; j < 16; ++j) {
            const unsigned n = (unsigned)(f >> (4 * j)) & 0xFu;
            v4u ov = (v4u){n & 1u, (n >> 1) & 1u, (n >> 2) & 1u, (n >> 3) & 1u};
            __builtin_nontemporal_store(ov, &qo[(size_t)(kk * 16 + j) * B4]);
        }
    }
}

extern "C" void kernel_launch(void* const* d_in, const int* in_sizes, int n_in,
                              void* d_out, int out_size, void* d_ws, size_t ws_size,
                              hipStream_t stream) {
    const v4u* in = (const v4u*)d_in[0];
    v4u* out = (v4u*)d_out;
    unsigned* ctl = (unsigned*)d_ws;  // [0..63] ctl, then agg + inc (512 KB each)

    xor_sc0<<<NBLK, TPB, 0, stream>>>(in, out, ctl);
}